// Round 1
// baseline (162.343 us; speedup 1.0000x reference)
//
#include <hip/hip_runtime.h>
#include <hip/hip_bf16.h>

// Problem constants
#define M_DIM 256     // B*T = 8*32
#define K_DIM 8192    // output features
#define N_DIM 8192    // reduction dim
#define NGRP  64      // N / 128 group count (groups along n)

// Main GEMM tile config
#define BN 128        // out-k columns per block
#define BK 64         // n (reduction) per step
#define THREADS 512   // 8 waves: 2 (m) x 4 (k)
#define LDPAD 8       // +8 bf16 pad -> 144B row stride (2-way bank alias = free)

typedef __bf16 bf16x8 __attribute__((ext_vector_type(8)));
typedef __bf16 bf16x4 __attribute__((ext_vector_type(4)));
typedef float  f32x4  __attribute__((ext_vector_type(4)));

// ---------------- Kernel 0: xs[m,n] = bf16(x[m,n] * mu1[n]) ----------------
__global__ __launch_bounds__(256) void prep_xs(const float* __restrict__ x,
                                               const float* __restrict__ mu1,
                                               __bf16* __restrict__ xs) {
    int t  = blockIdx.x * 256 + threadIdx.x;   // one thread per 4 elements
    int n4 = t & 2047;                         // N/4 = 2048
    int m  = t >> 11;
    int n  = n4 << 2;
    float4 xv = *(const float4*)(x + (size_t)m * N_DIM + n);
    float4 mv = *(const float4*)(mu1 + n);
    bf16x4 o;
    o[0] = (__bf16)(xv.x * mv.x);
    o[1] = (__bf16)(xv.y * mv.y);
    o[2] = (__bf16)(xv.z * mv.z);
    o[3] = (__bf16)(xv.w * mv.w);
    *(bf16x4*)(xs + (size_t)m * N_DIM + n) = o;
}

// ---------------- Kernel 1: partial[split][m][k] = sum_{n in chunk} xs*Wdeq ----------------
// Wdeq (sans mu2) = (Wq - zeros[k,g]) * scales[k,g], dequantized to bf16 into LDS.
__global__ __launch_bounds__(THREADS, 2)
void gemm_q(const __bf16* __restrict__ xs, const int* __restrict__ Wq,
            const float* __restrict__ scales, const float* __restrict__ zeros,
            float* __restrict__ partial, int chunk) {
    __shared__ __bf16 As[M_DIM][BK + LDPAD];   // 256 x 72 bf16 = 36 KB
    __shared__ __bf16 Bs[BN][BK + LDPAD];      // 128 x 72 bf16 = 18 KB

    const int k0    = blockIdx.x * BN;
    const int split = blockIdx.y;
    const int nbase = split * chunk;
    const int tid   = threadIdx.x;
    const int lane  = tid & 63;
    const int w     = tid >> 6;   // 0..7
    const int wm    = w >> 2;     // 0..1  (m half: 128 rows)
    const int wn    = w & 3;      // 0..3  (k quarter: 32 cols)

    // staging coordinates
    const int axr = tid >> 3;          // xs row in 64-row round (8 thr/row * 16B)
    const int axc = (tid & 7) * 8;     // bf16 col
    const int wxr = tid >> 4;          // W row in 32-row round (16 thr/row * 16B)
    const int wxc = (tid & 15) * 4;    // int32 col

    f32x4 acc[8][2];
#pragma unroll
    for (int i = 0; i < 8; ++i)
#pragma unroll
        for (int j = 0; j < 2; ++j)
            acc[i][j] = (f32x4){0.f, 0.f, 0.f, 0.f};

    const int nsteps = chunk / BK;
    for (int it = 0; it < nsteps; ++it) {
        const int n0 = nbase + it * BK;
        // ---- stage xs tile [256][64] ----
#pragma unroll
        for (int r = 0; r < 4; ++r) {
            int row = r * 64 + axr;
            uint4 v = *(const uint4*)(xs + (size_t)row * N_DIM + n0 + axc);
            *(uint4*)&As[row][axc] = v;
        }
        // ---- stage + dequant W tile [128][64] ----
        const int g = n0 >> 7;  // group index (BK=64 never straddles a 128-group)
#pragma unroll
        for (int r = 0; r < 4; ++r) {
            int row = r * 32 + wxr;       // local out-k row 0..127
            int gk  = k0 + row;
            int4 q  = *(const int4*)(Wq + (size_t)gk * N_DIM + n0 + wxc);
            float s = scales[gk * NGRP + g];
            float z = zeros [gk * NGRP + g];
            bf16x4 wv;
            wv[0] = (__bf16)(((float)q.x - z) * s);
            wv[1] = (__bf16)(((float)q.y - z) * s);
            wv[2] = (__bf16)(((float)q.z - z) * s);
            wv[3] = (__bf16)(((float)q.w - z) * s);
            *(bf16x4*)&Bs[row][wxc] = wv;
        }
        __syncthreads();
        // ---- MFMA: 32 per wave per step ----
#pragma unroll
        for (int h = 0; h < 2; ++h) {
            bf16x8 b[2];
#pragma unroll
            for (int ci = 0; ci < 2; ++ci)
                b[ci] = *(const bf16x8*)&Bs[wn * 32 + ci * 16 + (lane & 15)][h * 32 + (lane >> 4) * 8];
#pragma unroll
            for (int mi = 0; mi < 8; ++mi) {
                bf16x8 a = *(const bf16x8*)&As[wm * 128 + mi * 16 + (lane & 15)][h * 32 + (lane >> 4) * 8];
#pragma unroll
                for (int ci = 0; ci < 2; ++ci)
                    acc[mi][ci] = __builtin_amdgcn_mfma_f32_16x16x32_bf16(a, b[ci], acc[mi][ci], 0, 0, 0);
            }
        }
        __syncthreads();
    }

    // ---- epilogue: write fp32 partials (C/D layout: col=lane&15, row=(lane>>4)*4+reg) ----
    float* outp = partial + (size_t)split * ((size_t)M_DIM * K_DIM);
#pragma unroll
    for (int mi = 0; mi < 8; ++mi) {
#pragma unroll
        for (int ci = 0; ci < 2; ++ci) {
            int gk = k0 + wn * 32 + ci * 16 + (lane & 15);
            int gm = wm * 128 + mi * 16 + (lane >> 4) * 4;
#pragma unroll
            for (int rix = 0; rix < 4; ++rix)
                outp[(size_t)(gm + rix) * K_DIM + gk] = acc[mi][ci][rix];
        }
    }
}

// ---------------- Kernel 2: out = mu2[k] * sum_splits + bias[k] ----------------
__global__ __launch_bounds__(256) void reduce_out(const float* __restrict__ partial,
                                                  const float* __restrict__ mu2,
                                                  const float* __restrict__ bias,
                                                  float* __restrict__ out, int splitn) {
    int t  = blockIdx.x * 256 + threadIdx.x;  // one thread per 4 outputs
    int k4 = t & 2047;                        // K/4 = 2048
    int m  = t >> 11;
    size_t base = (size_t)m * K_DIM + (size_t)k4 * 4;
    float4 s = *(const float4*)(partial + base);
    for (int sp = 1; sp < splitn; ++sp) {
        float4 p = *(const float4*)(partial + (size_t)sp * ((size_t)M_DIM * K_DIM) + base);
        s.x += p.x; s.y += p.y; s.z += p.z; s.w += p.w;
    }
    float4 m2 = *(const float4*)(mu2 + (size_t)k4 * 4);
    float4 b  = *(const float4*)(bias + (size_t)k4 * 4);
    float4 o;
    o.x = s.x * m2.x + b.x;
    o.y = s.y * m2.y + b.y;
    o.z = s.z * m2.z + b.z;
    o.w = s.w * m2.w + b.w;
    *(float4*)(out + base) = o;
}

extern "C" void kernel_launch(void* const* d_in, const int* in_sizes, int n_in,
                              void* d_out, int out_size, void* d_ws, size_t ws_size,
                              hipStream_t stream) {
    const float* x      = (const float*)d_in[0];
    const int*   Wq     = (const int*)d_in[1];
    const float* scales = (const float*)d_in[2];
    const float* zeros  = (const float*)d_in[3];
    const float* mu1    = (const float*)d_in[4];
    const float* mu2    = (const float*)d_in[5];
    const float* bias   = (const float*)d_in[6];
    float* out = (float*)d_out;

    __bf16* xs = (__bf16*)d_ws;
    const size_t xs_bytes = (size_t)M_DIM * N_DIM * sizeof(__bf16);        // 4 MB
    float* partial = (float*)((char*)d_ws + xs_bytes);
    const size_t part_bytes = (size_t)M_DIM * K_DIM * sizeof(float);       // 8 MB per split

    int splitn = 1;
    if (ws_size >= xs_bytes + 4 * part_bytes)      splitn = 4;
    else if (ws_size >= xs_bytes + 2 * part_bytes) splitn = 2;
    const int chunk = N_DIM / splitn;

    prep_xs<<<2048, 256, 0, stream>>>(x, mu1, xs);
    gemm_q<<<dim3(K_DIM / BN, splitn), THREADS, 0, stream>>>(xs, Wq, scales, zeros, partial, chunk);
    reduce_out<<<2048, 256, 0, stream>>>(partial, mu2, bias, out, splitn);
}

// Round 2
// 145.653 us; speedup vs baseline: 1.1146x; 1.1146x over previous
//
#include <hip/hip_runtime.h>
#include <hip/hip_bf16.h>

// Problem constants
#define M_DIM 256     // B*T = 8*32
#define K_DIM 8192    // output features
#define N_DIM 8192    // reduction dim
#define NGRP  64      // N/128 groups along n

// GEMM tile config
#define BN 128        // out-k rows of W per block
#define BK 32         // n (reduction) per step
#define THREADS 512   // 8 waves: 2 (m) x 4 (k)

typedef __bf16 bf16x8 __attribute__((ext_vector_type(8)));
typedef __bf16 bf16x4 __attribute__((ext_vector_type(4)));
typedef float  f32x4  __attribute__((ext_vector_type(4)));

// XOR swizzle (both-sides): spreads rows across 16B bank-slots; involution.
// Works for both A rows (64B) and B rows (128B): <=2-way conflict on all frag reads.
#define SW(a) ((a) ^ ((((a) >> 7) & 7) << 4))

#define GLOAD_LDS16(g, l) __builtin_amdgcn_global_load_lds( \
    (const __attribute__((address_space(1))) void*)(g),     \
    (__attribute__((address_space(3))) void*)(l), 16, 0, 0)

// ---------------- Kernel 0: xs[m,n] = bf16(x[m,n] * mu1[n]) ----------------
__global__ __launch_bounds__(256) void prep_xs(const float* __restrict__ x,
                                               const float* __restrict__ mu1,
                                               __bf16* __restrict__ xs) {
    int t  = blockIdx.x * 256 + threadIdx.x;   // one thread per 4 elements
    int n4 = t & 2047;                         // N/4 = 2048
    int m  = t >> 11;
    int n  = n4 << 2;
    float4 xv = *(const float4*)(x + (size_t)m * N_DIM + n);
    float4 mv = *(const float4*)(mu1 + n);
    bf16x4 o;
    o[0] = (__bf16)(xv.x * mv.x);
    o[1] = (__bf16)(xv.y * mv.y);
    o[2] = (__bf16)(xv.z * mv.z);
    o[3] = (__bf16)(xv.w * mv.w);
    *(bf16x4*)(xs + (size_t)m * N_DIM + n) = o;
}

// ---------------- Kernel 1: async-pipelined split-K GEMM ----------------
// LDS per buffer: As raw bf16 [256][32] = 16KB @0, Bs raw int32 [128][32] = 16KB @16K.
// Double buffered = 64KB static. W dequantized at fragment-load time.
__global__ __launch_bounds__(THREADS, 2)
void gemm_q(const __bf16* __restrict__ xs, const int* __restrict__ Wq,
            const float* __restrict__ scales, const float* __restrict__ zeros,
            float* __restrict__ partial, int chunk) {
    __shared__ __align__(1024) char lds[2][32768];

    const int k0    = blockIdx.x * BN;
    const int split = blockIdx.y;
    const int nbase = split * chunk;
    const int tid   = threadIdx.x;
    const int lane  = tid & 63;
    const int w     = tid >> 6;   // 0..7
    const int wm    = w >> 2;     // 0..1  (m half: 128 rows)
    const int wn    = w & 3;      // 0..3  (k quarter: 32 cols)

    // ---- staging precompute: 4 x 1KB LDS chunks per wave ----
    // waves 0-3 stage As (16 chunks), waves 4-7 stage Bs (16 chunks).
    // LDS dest is LINEAR (global_load_lds constraint); the SOURCE address is
    // inverse-swizzled so reads apply SW() and see the right data.
    const char* sbase[4];
    int ldsoff[4];
    const int arrbase = (w < 4) ? 0 : 16384;
    const int nscale  = (w < 4) ? 2 : 4;   // bytes per n-element of the source
#pragma unroll
    for (int cc = 0; cc < 4; ++cc) {
        int c   = ((w < 4) ? w : (w - 4)) * 4 + cc;
        int off = c * 1024 + lane * 16;     // intra-array linear dest
        int L   = SW(off);                  // logical element to fetch
        ldsoff[cc] = off;
        if (w < 4) {
            int row = L >> 6;               // As row (64B rows)
            sbase[cc] = (const char*)xs + ((size_t)row * N_DIM) * 2 + (L & 63);
        } else {
            int row = L >> 7;               // Bs row (128B rows)
            sbase[cc] = (const char*)Wq + ((size_t)(k0 + row) * N_DIM) * 4 + (L & 127);
        }
    }

    f32x4 acc[8][2];
#pragma unroll
    for (int i = 0; i < 8; ++i) {
        acc[i][0] = (f32x4){0.f, 0.f, 0.f, 0.f};
        acc[i][1] = (f32x4){0.f, 0.f, 0.f, 0.f};
    }

    const int gk0 = k0 + wn * 32 + (lane & 15);
    float sc0 = 0.f, sc1 = 0.f, zs0 = 0.f, zs1 = 0.f;

    const int nsteps = chunk / BK;

    // prologue: stage tile 0 into buf 0
    {
        char* base = &lds[0][arrbase];
#pragma unroll
        for (int cc = 0; cc < 4; ++cc)
            GLOAD_LDS16(sbase[cc] + (size_t)nbase * nscale, base + ldsoff[cc]);
    }

    for (int it = 0; it < nsteps; ++it) {
        const int n0  = nbase + it * BK;
        const int buf = it & 1;

        // tile `it` fully staged across all waves
        asm volatile("s_waitcnt vmcnt(0)" ::: "memory");
        __builtin_amdgcn_s_barrier();

        // issue next tile's loads (into the buffer everyone finished reading
        // at it-1; barrier above guarantees safety). Waited one iter later.
        if (it + 1 < nsteps) {
            char* base = &lds[buf ^ 1][arrbase];
            const size_t soff = (size_t)(n0 + BK) * nscale;
#pragma unroll
            for (int cc = 0; cc < 4; ++cc)
                GLOAD_LDS16(sbase[cc] + soff, base + ldsoff[cc]);
        }

        // group scale/zero refresh (group = 128 n = 4 steps)
        if ((it & 3) == 0) {
            int g = n0 >> 7;
            float z0, z1;
            sc0 = scales[gk0 * NGRP + g];
            z0  = zeros [gk0 * NGRP + g];
            sc1 = scales[(gk0 + 16) * NGRP + g];
            z1  = zeros [(gk0 + 16) * NGRP + g];
            zs0 = -z0 * sc0;
            zs1 = -z1 * sc1;
        }

        const char* bufA = &lds[buf][0];
        const char* bufB = bufA + 16384;

        // ---- B fragments: read raw codes, dequant to bf16 ----
        bf16x8 bv[2];
#pragma unroll
        for (int ci = 0; ci < 2; ++ci) {
            int lb = (wn * 32 + ci * 16 + (lane & 15)) * 128 + (lane >> 4) * 32;
            int pb = SW(lb);
            int4 q0 = *(const int4*)(bufB + pb);
            int4 q1 = *(const int4*)(bufB + (pb ^ 16));
            float s = ci ? sc1 : sc0;
            float z = ci ? zs1 : zs0;
            bv[ci][0] = (__bf16)((float)q0.x * s + z);
            bv[ci][1] = (__bf16)((float)q0.y * s + z);
            bv[ci][2] = (__bf16)((float)q0.z * s + z);
            bv[ci][3] = (__bf16)((float)q0.w * s + z);
            bv[ci][4] = (__bf16)((float)q1.x * s + z);
            bv[ci][5] = (__bf16)((float)q1.y * s + z);
            bv[ci][6] = (__bf16)((float)q1.z * s + z);
            bv[ci][7] = (__bf16)((float)q1.w * s + z);
        }

        // ---- A fragments + MFMA ----
#pragma unroll
        for (int mi = 0; mi < 8; ++mi) {
            int la = (wm * 128 + mi * 16 + (lane & 15)) * 64 + (lane >> 4) * 16;
            int pa = SW(la);
            bf16x8 av = *(const bf16x8*)(bufA + pa);
            acc[mi][0] = __builtin_amdgcn_mfma_f32_16x16x32_bf16(av, bv[0], acc[mi][0], 0, 0, 0);
            acc[mi][1] = __builtin_amdgcn_mfma_f32_16x16x32_bf16(av, bv[1], acc[mi][1], 0, 0, 0);
        }
    }

    // ---- epilogue: fp32 partials (C/D layout: col=lane&15, row=(lane>>4)*4+reg) ----
    float* outp = partial + (size_t)split * ((size_t)M_DIM * K_DIM);
#pragma unroll
    for (int mi = 0; mi < 8; ++mi) {
#pragma unroll
        for (int ci = 0; ci < 2; ++ci) {
            int gk = k0 + wn * 32 + ci * 16 + (lane & 15);
            int gm = wm * 128 + mi * 16 + (lane >> 4) * 4;
#pragma unroll
            for (int rix = 0; rix < 4; ++rix)
                outp[(size_t)(gm + rix) * K_DIM + gk] = acc[mi][ci][rix];
        }
    }
}

// ---------------- Kernel 2: out = mu2[k] * sum_splits + bias[k] ----------------
__global__ __launch_bounds__(256) void reduce_out(const float* __restrict__ partial,
                                                  const float* __restrict__ mu2,
                                                  const float* __restrict__ bias,
                                                  float* __restrict__ out, int splitn) {
    int t  = blockIdx.x * 256 + threadIdx.x;  // one thread per 4 outputs
    int k4 = t & 2047;                        // K/4 = 2048
    int m  = t >> 11;
    size_t base = (size_t)m * K_DIM + (size_t)k4 * 4;
    float4 s = *(const float4*)(partial + base);
    for (int sp = 1; sp < splitn; ++sp) {
        float4 p = *(const float4*)(partial + (size_t)sp * ((size_t)M_DIM * K_DIM) + base);
        s.x += p.x; s.y += p.y; s.z += p.z; s.w += p.w;
    }
    float4 m2 = *(const float4*)(mu2 + (size_t)k4 * 4);
    float4 b  = *(const float4*)(bias + (size_t)k4 * 4);
    float4 o;
    o.x = s.x * m2.x + b.x;
    o.y = s.y * m2.y + b.y;
    o.z = s.z * m2.z + b.z;
    o.w = s.w * m2.w + b.w;
    *(float4*)(out + base) = o;
}

extern "C" void kernel_launch(void* const* d_in, const int* in_sizes, int n_in,
                              void* d_out, int out_size, void* d_ws, size_t ws_size,
                              hipStream_t stream) {
    const float* x      = (const float*)d_in[0];
    const int*   Wq     = (const int*)d_in[1];
    const float* scales = (const float*)d_in[2];
    const float* zeros  = (const float*)d_in[3];
    const float* mu1    = (const float*)d_in[4];
    const float* mu2    = (const float*)d_in[5];
    const float* bias   = (const float*)d_in[6];
    float* out = (float*)d_out;

    __bf16* xs = (__bf16*)d_ws;
    const size_t xs_bytes = (size_t)M_DIM * N_DIM * sizeof(__bf16);        // 4 MB
    float* partial = (float*)((char*)d_ws + xs_bytes);
    const size_t part_bytes = (size_t)M_DIM * K_DIM * sizeof(float);       // 8 MB per split

    int splitn = 1;
    if (ws_size >= xs_bytes + 4 * part_bytes)      splitn = 4;
    else if (ws_size >= xs_bytes + 2 * part_bytes) splitn = 2;
    const int chunk = N_DIM / splitn;

    prep_xs<<<2048, 256, 0, stream>>>(x, mu1, xs);
    gemm_q<<<dim3(K_DIM / BN, splitn), THREADS, 0, stream>>>(xs, Wq, scales, zeros, partial, chunk);
    reduce_out<<<2048, 256, 0, stream>>>(partial, mu2, bias, out, splitn);
}

// Round 3
// 134.178 us; speedup vs baseline: 1.2099x; 1.0855x over previous
//
#include <hip/hip_runtime.h>
#include <hip/hip_bf16.h>

// Problem constants
#define M_DIM 256     // B*T = 8*32
#define K_DIM 8192    // output features
#define N_DIM 8192    // reduction dim
#define NGRP  64      // N/128 groups along n

// GEMM tile config
#define BN 128        // out-k rows of W per block
#define BK 32         // n (reduction) per step
#define THREADS 512   // 8 waves: 2 (m) x 4 (k)
#define DEPTH 4       // LDS pipeline buffers (3 tiles in flight)
#define TILE_BYTES 32768   // As 16KB (bf16 [256][32]) + Bs 16KB (int32 [128][32])

typedef __bf16 bf16x8 __attribute__((ext_vector_type(8)));
typedef __bf16 bf16x4 __attribute__((ext_vector_type(4)));
typedef float  f32x4  __attribute__((ext_vector_type(4)));

// XOR swizzle (both-sides involution): permutes 16B granules within 128B blocks.
#define SW(a) ((a) ^ ((((a) >> 7) & 7) << 4))

#define GLOAD_LDS16(g, l) __builtin_amdgcn_global_load_lds( \
    (const __attribute__((address_space(1))) void*)(g),     \
    (__attribute__((address_space(3))) void*)(l), 16, 0, 0)

// ---------------- Kernel 0: xs[m,n] = bf16(x[m,n] * mu1[n]) ----------------
__global__ __launch_bounds__(256) void prep_xs(const float* __restrict__ x,
                                               const float* __restrict__ mu1,
                                               __bf16* __restrict__ xs) {
    int t  = blockIdx.x * 256 + threadIdx.x;
    int n4 = t & 2047;
    int m  = t >> 11;
    int n  = n4 << 2;
    float4 xv = *(const float4*)(x + (size_t)m * N_DIM + n);
    float4 mv = *(const float4*)(mu1 + n);
    bf16x4 o;
    o[0] = (__bf16)(xv.x * mv.x);
    o[1] = (__bf16)(xv.y * mv.y);
    o[2] = (__bf16)(xv.z * mv.z);
    o[3] = (__bf16)(xv.w * mv.w);
    *(bf16x4*)(xs + (size_t)m * N_DIM + n) = o;
}

// ---------------- Kernel 1: deep-pipelined split-K GEMM ----------------
__global__ __launch_bounds__(THREADS, 2)
void gemm_q(const __bf16* __restrict__ xs, const int* __restrict__ Wq,
            const float* __restrict__ scales, const float* __restrict__ zeros,
            float* __restrict__ partial, int chunk, int splitn) {
    extern __shared__ __align__(1024) char lds[];  // DEPTH*32KB tiles + scales

    // ---- XCD-affinity work mapping: blocks on one XCD share a split (A-chunk) ----
    const int b    = blockIdx.x;
    const int nx   = 8 / splitn;             // XCDs per split
    const int r7   = b & 7;
    const int split = r7 / nx;
    const int kidx  = (b >> 3) * nx + (r7 % nx);
    const int k0    = kidx * BN;
    const int nbase = split * chunk;
    const int NG    = chunk >> 7;            // groups in this chunk
    const int gbase = split * NG;

    const int tid   = threadIdx.x;
    const int lane  = tid & 63;
    const int w     = tid >> 6;   // 0..7
    const int wm    = w >> 2;     // 0..1  (m half: 128 rows)
    const int wn    = w & 3;      // 0..3  (k quarter: 32 cols)

    float* SL = (float*)(lds + DEPTH * TILE_BYTES);  // [NG][128][2] = {s, -z*s}

    // ---- stage scales/zeros to LDS (one time; keeps K-loop free of VMEM) ----
    {
        int r  = tid >> 2;        // 0..127
        int gq = tid & 3;
        for (int gg = 0; gg < (NG >> 2); ++gg) {
            int g = (gg << 2) | gq;
            size_t si = (size_t)(k0 + r) * NGRP + gbase + g;
            float s = scales[si];
            float z = zeros[si];
            float2 v; v.x = s; v.y = -z * s;
            *(float2*)&SL[(size_t)((g << 7) + r) * 2] = v;
        }
    }

    // ---- staging precompute: 4 x 1KB LDS chunks per wave ----
    // waves 0-3 stage As, waves 4-7 stage Bs. LDS dest LINEAR, source inverse-swizzled.
    const char* sbase[4];
    int ldsoff[4];
    const int arrbase = (w < 4) ? 0 : 16384;
    const int nscale  = (w < 4) ? 2 : 4;   // bytes per n-element
#pragma unroll
    for (int cc = 0; cc < 4; ++cc) {
        int c   = ((w < 4) ? w : (w - 4)) * 4 + cc;
        int off = c * 1024 + lane * 16;
        int L   = SW(off);
        ldsoff[cc] = off;
        if (w < 4) {
            int row = L >> 6;
            sbase[cc] = (const char*)xs + ((size_t)row * N_DIM) * 2 + (L & 63);
        } else {
            int row = L >> 7;
            sbase[cc] = (const char*)Wq + ((size_t)(k0 + row) * N_DIM) * 4 + (L & 127);
        }
    }

#define ISSUE_TILE(t, bi)                                              \
    {                                                                  \
        char* base_ = lds + (bi) * TILE_BYTES + arrbase;               \
        const size_t soff_ = (size_t)(nbase + (t) * BK) * nscale;      \
        _Pragma("unroll")                                              \
        for (int cc = 0; cc < 4; ++cc)                                 \
            GLOAD_LDS16(sbase[cc] + soff_, base_ + ldsoff[cc]);        \
    }

    f32x4 acc[8][2];
#pragma unroll
    for (int i = 0; i < 8; ++i) {
        acc[i][0] = (f32x4){0.f, 0.f, 0.f, 0.f};
        acc[i][1] = (f32x4){0.f, 0.f, 0.f, 0.f};
    }

    const int nsteps = chunk / BK;

    // prologue: 3 tiles in flight
    ISSUE_TILE(0, 0);
    ISSUE_TILE(1, 1);
    ISSUE_TILE(2, 2);
    asm volatile("s_waitcnt lgkmcnt(0)" ::: "memory");  // scale ds_writes drained

    float sc0 = 0.f, sc1 = 0.f, zs0 = 0.f, zs1 = 0.f;
    const int srow = wn * 32 + (lane & 15);

    for (int it = 0; it < nsteps; ++it) {
        const int buf = it & 3;

        // counted waits: steady state keeps 2 tiles (8 loads) in flight
        if (it < nsteps - 2)       asm volatile("s_waitcnt vmcnt(8)" ::: "memory");
        else if (it == nsteps - 2) asm volatile("s_waitcnt vmcnt(4)" ::: "memory");
        else                       asm volatile("s_waitcnt vmcnt(0)" ::: "memory");
        __builtin_amdgcn_s_barrier();

        if (it + 3 < nsteps) ISSUE_TILE(it + 3, (it + 3) & 3);

        if ((it & 3) == 0) {
            int g = it >> 2;
            float2 v0 = *(float2*)&SL[(size_t)((g << 7) + srow) * 2];
            float2 v1 = *(float2*)&SL[(size_t)((g << 7) + srow + 16) * 2];
            sc0 = v0.x; zs0 = v0.y;
            sc1 = v1.x; zs1 = v1.y;
        }

        const char* bufA = lds + buf * TILE_BYTES;
        const char* bufB = bufA + 16384;

        // ---- B fragments: raw codes -> dequant to bf16 ----
        bf16x8 bv[2];
#pragma unroll
        for (int ci = 0; ci < 2; ++ci) {
            int lb = (wn * 32 + ci * 16 + (lane & 15)) * 128 + (lane >> 4) * 32;
            int pb = SW(lb);
            int4 q0 = *(const int4*)(bufB + pb);
            int4 q1 = *(const int4*)(bufB + (pb ^ 16));
            float s = ci ? sc1 : sc0;
            float z = ci ? zs1 : zs0;
            bv[ci][0] = (__bf16)((float)q0.x * s + z);
            bv[ci][1] = (__bf16)((float)q0.y * s + z);
            bv[ci][2] = (__bf16)((float)q0.z * s + z);
            bv[ci][3] = (__bf16)((float)q0.w * s + z);
            bv[ci][4] = (__bf16)((float)q1.x * s + z);
            bv[ci][5] = (__bf16)((float)q1.y * s + z);
            bv[ci][6] = (__bf16)((float)q1.z * s + z);
            bv[ci][7] = (__bf16)((float)q1.w * s + z);
        }

        // ---- A fragments + MFMA ----
#pragma unroll
        for (int mi = 0; mi < 8; ++mi) {
            int la = (wm * 128 + mi * 16 + (lane & 15)) * 64 + (lane >> 4) * 16;
            int pa = SW(la);
            bf16x8 av = *(const bf16x8*)(bufA + pa);
            acc[mi][0] = __builtin_amdgcn_mfma_f32_16x16x32_bf16(av, bv[0], acc[mi][0], 0, 0, 0);
            acc[mi][1] = __builtin_amdgcn_mfma_f32_16x16x32_bf16(av, bv[1], acc[mi][1], 0, 0, 0);
        }
    }

    // ---- epilogue: fp32 partials (C/D layout: col=lane&15, row=(lane>>4)*4+reg) ----
    float* outp = partial + (size_t)split * ((size_t)M_DIM * K_DIM);
#pragma unroll
    for (int mi = 0; mi < 8; ++mi) {
#pragma unroll
        for (int ci = 0; ci < 2; ++ci) {
            int gk = k0 + wn * 32 + ci * 16 + (lane & 15);
            int gm = wm * 128 + mi * 16 + (lane >> 4) * 4;
#pragma unroll
            for (int rix = 0; rix < 4; ++rix)
                outp[(size_t)(gm + rix) * K_DIM + gk] = acc[mi][ci][rix];
        }
    }
#undef ISSUE_TILE
}

// ---------------- Kernel 2: out = mu2[k] * sum_splits + bias[k] ----------------
__global__ __launch_bounds__(256) void reduce_out(const float* __restrict__ partial,
                                                  const float* __restrict__ mu2,
                                                  const float* __restrict__ bias,
                                                  float* __restrict__ out, int splitn) {
    int t  = blockIdx.x * 256 + threadIdx.x;
    int k4 = t & 2047;
    int m  = t >> 11;
    size_t base = (size_t)m * K_DIM + (size_t)k4 * 4;
    float4 s = *(const float4*)(partial + base);
    for (int sp = 1; sp < splitn; ++sp) {
        float4 p = *(const float4*)(partial + (size_t)sp * ((size_t)M_DIM * K_DIM) + base);
        s.x += p.x; s.y += p.y; s.z += p.z; s.w += p.w;
    }
    float4 m2 = *(const float4*)(mu2 + (size_t)k4 * 4);
    float4 b  = *(const float4*)(bias + (size_t)k4 * 4);
    float4 o;
    o.x = s.x * m2.x + b.x;
    o.y = s.y * m2.y + b.y;
    o.z = s.z * m2.z + b.z;
    o.w = s.w * m2.w + b.w;
    *(float4*)(out + base) = o;
}

extern "C" void kernel_launch(void* const* d_in, const int* in_sizes, int n_in,
                              void* d_out, int out_size, void* d_ws, size_t ws_size,
                              hipStream_t stream) {
    const float* x      = (const float*)d_in[0];
    const int*   Wq     = (const int*)d_in[1];
    const float* scales = (const float*)d_in[2];
    const float* zeros  = (const float*)d_in[3];
    const float* mu1    = (const float*)d_in[4];
    const float* mu2    = (const float*)d_in[5];
    const float* bias   = (const float*)d_in[6];
    float* out = (float*)d_out;

    __bf16* xs = (__bf16*)d_ws;
    const size_t xs_bytes = (size_t)M_DIM * N_DIM * sizeof(__bf16);        // 4 MB
    float* partial = (float*)((char*)d_ws + xs_bytes);
    const size_t part_bytes = (size_t)M_DIM * K_DIM * sizeof(float);       // 8 MB per split

    int splitn = (ws_size >= xs_bytes + 4 * part_bytes) ? 4 : 2;
    const int chunk = N_DIM / splitn;
    const int NG = chunk >> 7;
    const size_t shbytes = (size_t)DEPTH * TILE_BYTES + (size_t)NG * 128 * 2 * sizeof(float);

    (void)hipFuncSetAttribute((const void*)gemm_q,
                              hipFuncAttributeMaxDynamicSharedMemorySize,
                              (int)shbytes);

    prep_xs<<<2048, 256, 0, stream>>>(x, mu1, xs);
    gemm_q<<<64 * splitn, THREADS, shbytes, stream>>>(xs, Wq, scales, zeros, partial, chunk, splitn);
    reduce_out<<<2048, 256, 0, stream>>>(partial, mu2, bias, out, splitn);
}

// Round 4
// 129.433 us; speedup vs baseline: 1.2543x; 1.0367x over previous
//
#include <hip/hip_runtime.h>
#include <hip/hip_bf16.h>

// Problem constants
#define M_DIM 256     // B*T = 8*32
#define K_DIM 8192    // output features
#define N_DIM 8192    // reduction dim
#define NGRP  64      // N/128 groups along n

// GEMM tile config
#define BN 128        // out-k rows of W per block
#define BK 32         // n (reduction) per step
#define THREADS 512   // 8 waves: 2 (m) x 4 (k)
#define DEPTH 4       // LDS pipeline buffers (3 tiles in flight)
#define TILE_BYTES 32768   // As 16KB (bf16 [256][32]) + Bs 16KB (int32 [128][32])

typedef __bf16 bf16x8 __attribute__((ext_vector_type(8)));
typedef __bf16 bf16x4 __attribute__((ext_vector_type(4)));
typedef float  f32x4  __attribute__((ext_vector_type(4)));

// XOR swizzle (both-sides involution): permutes 16B granules within 128B blocks.
#define SW(a) ((a) ^ ((((a) >> 7) & 7) << 4))

#define GLOAD_LDS16(g, l) __builtin_amdgcn_global_load_lds( \
    (const __attribute__((address_space(1))) void*)(g),     \
    (__attribute__((address_space(3))) void*)(l), 16, 0, 0)

// ---------------- Kernel 0: xs[m,n] = bf16(x[m,n] * mu1[n]) ----------------
__global__ __launch_bounds__(256) void prep_xs(const float* __restrict__ x,
                                               const float* __restrict__ mu1,
                                               __bf16* __restrict__ xs) {
    int t  = blockIdx.x * 256 + threadIdx.x;
    int n4 = t & 2047;
    int m  = t >> 11;
    int n  = n4 << 2;
    float4 xv = *(const float4*)(x + (size_t)m * N_DIM + n);
    float4 mv = *(const float4*)(mu1 + n);
    bf16x4 o;
    o[0] = (__bf16)(xv.x * mv.x);
    o[1] = (__bf16)(xv.y * mv.y);
    o[2] = (__bf16)(xv.z * mv.z);
    o[3] = (__bf16)(xv.w * mv.w);
    *(bf16x4*)(xs + (size_t)m * N_DIM + n) = o;
}

// ---------------- Kernel 1: deep-pipelined split-K GEMM, n-rotated ----------------
__global__ __launch_bounds__(THREADS, 2)
void gemm_q(const __bf16* __restrict__ xs, const int* __restrict__ Wq,
            const float* __restrict__ scales, const float* __restrict__ zeros,
            float* __restrict__ partial, int chunk, int splitn) {
    extern __shared__ __align__(1024) char lds[];  // DEPTH*32KB tiles + scales

    // ---- XCD-affinity work mapping: blocks on one XCD share a split (A-chunk) ----
    const int b    = blockIdx.x;
    const int nx   = 8 / splitn;             // XCDs per split
    const int r7   = b & 7;
    const int split = r7 / nx;
    const int kidx  = (b >> 3) * nx + (r7 % nx);
    const int k0    = kidx * BN;
    const int nbase = split * chunk;
    const int NG    = chunk >> 7;            // groups in this chunk
    const int gbase = split * NG;

    const int tid   = threadIdx.x;
    const int lane  = tid & 63;
    const int w     = tid >> 6;   // 0..7
    const int wm    = w >> 2;     // 0..1  (m half: 128 rows)
    const int wn    = w & 3;      // 0..3  (k quarter: 32 cols)

    const int nsteps = chunk / BK;           // power of two (64 or 128)
    const int smask  = nsteps - 1;
    // n-rotation: each kidx starts at a different n-phase so chip-wide address
    // bits 7..14 are decorrelated (kills the HBM/L2 channel convoy).
    const int start  = kidx & smask;

    float* SL = (float*)(lds + DEPTH * TILE_BYTES);  // [NG][128][2] = {s, -z*s}

    // ---- stage scales/zeros to LDS (one time; keeps K-loop free of VMEM) ----
    {
        int r  = tid >> 2;        // 0..127
        int gq = tid & 3;
        for (int gg = 0; gg < (NG >> 2); ++gg) {
            int g = (gg << 2) | gq;
            size_t si = (size_t)(k0 + r) * NGRP + gbase + g;
            float s = scales[si];
            float z = zeros[si];
            float2 v; v.x = s; v.y = -z * s;
            *(float2*)&SL[(size_t)((g << 7) + r) * 2] = v;
        }
    }

    // ---- staging precompute: 4 x 1KB LDS chunks per wave ----
    // waves 0-3 stage As, waves 4-7 stage Bs. LDS dest LINEAR, source inverse-swizzled.
    const char* sbase[4];
    int ldsoff[4];
    const int arrbase = (w < 4) ? 0 : 16384;
    const int nscale  = (w < 4) ? 2 : 4;   // bytes per n-element
#pragma unroll
    for (int cc = 0; cc < 4; ++cc) {
        int c   = ((w < 4) ? w : (w - 4)) * 4 + cc;
        int off = c * 1024 + lane * 16;
        int L   = SW(off);
        ldsoff[cc] = off;
        if (w < 4) {
            int row = L >> 6;
            sbase[cc] = (const char*)xs + ((size_t)row * N_DIM) * 2 + (L & 63);
        } else {
            int row = L >> 7;
            sbase[cc] = (const char*)Wq + ((size_t)(k0 + row) * N_DIM) * 4 + (L & 127);
        }
    }

#define ISSUE_TILE(t, bi)                                              \
    {                                                                  \
        char* base_ = lds + (bi) * TILE_BYTES + arrbase;               \
        const int s_ = ((t) + start) & smask;                          \
        const size_t soff_ = (size_t)(nbase + s_ * BK) * nscale;       \
        _Pragma("unroll")                                              \
        for (int cc = 0; cc < 4; ++cc)                                 \
            GLOAD_LDS16(sbase[cc] + soff_, base_ + ldsoff[cc]);        \
    }

    f32x4 acc[8][2];
#pragma unroll
    for (int i = 0; i < 8; ++i) {
        acc[i][0] = (f32x4){0.f, 0.f, 0.f, 0.f};
        acc[i][1] = (f32x4){0.f, 0.f, 0.f, 0.f};
    }

    // prologue: 3 tiles in flight
    ISSUE_TILE(0, 0);
    ISSUE_TILE(1, 1);
    ISSUE_TILE(2, 2);
    asm volatile("s_waitcnt lgkmcnt(0)" ::: "memory");  // scale ds_writes drained

    float sc0 = 0.f, sc1 = 0.f, zs0 = 0.f, zs1 = 0.f;
    const int srow = wn * 32 + (lane & 15);

    for (int it = 0; it < nsteps; ++it) {
        const int buf = it & 3;
        const int s   = (it + start) & smask;   // rotated (actual) step

        // counted waits: steady state keeps 2 tiles (8 loads) in flight
        if (it < nsteps - 2)       asm volatile("s_waitcnt vmcnt(8)" ::: "memory");
        else if (it == nsteps - 2) asm volatile("s_waitcnt vmcnt(4)" ::: "memory");
        else                       asm volatile("s_waitcnt vmcnt(0)" ::: "memory");
        __builtin_amdgcn_s_barrier();

        if (it + 3 < nsteps) ISSUE_TILE(it + 3, (it + 3) & 3);

        // group scale/zero refresh keyed to rotated step
        if ((s & 3) == 0 || it == 0) {
            int g = s >> 2;
            float2 v0 = *(float2*)&SL[(size_t)((g << 7) + srow) * 2];
            float2 v1 = *(float2*)&SL[(size_t)((g << 7) + srow + 16) * 2];
            sc0 = v0.x; zs0 = v0.y;
            sc1 = v1.x; zs1 = v1.y;
        }

        const char* bufA = lds + buf * TILE_BYTES;
        const char* bufB = bufA + 16384;

        // ---- B fragments: raw codes -> dequant to bf16 ----
        bf16x8 bv[2];
#pragma unroll
        for (int ci = 0; ci < 2; ++ci) {
            int lb = (wn * 32 + ci * 16 + (lane & 15)) * 128 + (lane >> 4) * 32;
            int pb = SW(lb);
            int4 q0 = *(const int4*)(bufB + pb);
            int4 q1 = *(const int4*)(bufB + (pb ^ 16));
            float ss = ci ? sc1 : sc0;
            float zz = ci ? zs1 : zs0;
            bv[ci][0] = (__bf16)((float)q0.x * ss + zz);
            bv[ci][1] = (__bf16)((float)q0.y * ss + zz);
            bv[ci][2] = (__bf16)((float)q0.z * ss + zz);
            bv[ci][3] = (__bf16)((float)q0.w * ss + zz);
            bv[ci][4] = (__bf16)((float)q1.x * ss + zz);
            bv[ci][5] = (__bf16)((float)q1.y * ss + zz);
            bv[ci][6] = (__bf16)((float)q1.z * ss + zz);
            bv[ci][7] = (__bf16)((float)q1.w * ss + zz);
        }

        // ---- A fragments + MFMA ----
#pragma unroll
        for (int mi = 0; mi < 8; ++mi) {
            int la = (wm * 128 + mi * 16 + (lane & 15)) * 64 + (lane >> 4) * 16;
            int pa = SW(la);
            bf16x8 av = *(const bf16x8*)(bufA + pa);
            acc[mi][0] = __builtin_amdgcn_mfma_f32_16x16x32_bf16(av, bv[0], acc[mi][0], 0, 0, 0);
            acc[mi][1] = __builtin_amdgcn_mfma_f32_16x16x32_bf16(av, bv[1], acc[mi][1], 0, 0, 0);
        }
    }

    // ---- epilogue: fp32 partials (C/D layout: col=lane&15, row=(lane>>4)*4+reg) ----
    float* outp = partial + (size_t)split * ((size_t)M_DIM * K_DIM);
#pragma unroll
    for (int mi = 0; mi < 8; ++mi) {
#pragma unroll
        for (int ci = 0; ci < 2; ++ci) {
            int gk = k0 + wn * 32 + ci * 16 + (lane & 15);
            int gm = wm * 128 + mi * 16 + (lane >> 4) * 4;
#pragma unroll
            for (int rix = 0; rix < 4; ++rix)
                outp[(size_t)(gm + rix) * K_DIM + gk] = acc[mi][ci][rix];
        }
    }
#undef ISSUE_TILE
}

// ---------------- Kernel 2: out = mu2[k] * sum_splits + bias[k] ----------------
__global__ __launch_bounds__(256) void reduce_out(const float* __restrict__ partial,
                                                  const float* __restrict__ mu2,
                                                  const float* __restrict__ bias,
                                                  float* __restrict__ out, int splitn) {
    int t  = blockIdx.x * 256 + threadIdx.x;
    int k4 = t & 2047;
    int m  = t >> 11;
    size_t base = (size_t)m * K_DIM + (size_t)k4 * 4;
    float4 s = *(const float4*)(partial + base);
    for (int sp = 1; sp < splitn; ++sp) {
        float4 p = *(const float4*)(partial + (size_t)sp * ((size_t)M_DIM * K_DIM) + base);
        s.x += p.x; s.y += p.y; s.z += p.z; s.w += p.w;
    }
    float4 m2 = *(const float4*)(mu2 + (size_t)k4 * 4);
    float4 b  = *(const float4*)(bias + (size_t)k4 * 4);
    float4 o;
    o.x = s.x * m2.x + b.x;
    o.y = s.y * m2.y + b.y;
    o.z = s.z * m2.z + b.z;
    o.w = s.w * m2.w + b.w;
    *(float4*)(out + base) = o;
}

extern "C" void kernel_launch(void* const* d_in, const int* in_sizes, int n_in,
                              void* d_out, int out_size, void* d_ws, size_t ws_size,
                              hipStream_t stream) {
    const float* x      = (const float*)d_in[0];
    const int*   Wq     = (const int*)d_in[1];
    const float* scales = (const float*)d_in[2];
    const float* zeros  = (const float*)d_in[3];
    const float* mu1    = (const float*)d_in[4];
    const float* mu2    = (const float*)d_in[5];
    const float* bias   = (const float*)d_in[6];
    float* out = (float*)d_out;

    __bf16* xs = (__bf16*)d_ws;
    const size_t xs_bytes = (size_t)M_DIM * N_DIM * sizeof(__bf16);        // 4 MB
    float* partial = (float*)((char*)d_ws + xs_bytes);
    const size_t part_bytes = (size_t)M_DIM * K_DIM * sizeof(float);       // 8 MB per split

    int splitn = (ws_size >= xs_bytes + 4 * part_bytes) ? 4 : 2;
    const int chunk = N_DIM / splitn;
    const int NG = chunk >> 7;
    const size_t shbytes = (size_t)DEPTH * TILE_BYTES + (size_t)NG * 128 * 2 * sizeof(float);

    (void)hipFuncSetAttribute((const void*)gemm_q,
                              hipFuncAttributeMaxDynamicSharedMemorySize,
                              (int)shbytes);

    prep_xs<<<2048, 256, 0, stream>>>(x, mu1, xs);
    gemm_q<<<64 * splitn, THREADS, shbytes, stream>>>(xs, Wq, scales, zeros, partial, chunk, splitn);
    reduce_out<<<2048, 256, 0, stream>>>(partial, mu2, bias, out, splitn);
}

// Round 5
// 97.695 us; speedup vs baseline: 1.6617x; 1.3249x over previous
//
#include <hip/hip_runtime.h>
#include <hip/hip_bf16.h>

// Problem constants
#define M_DIM 256     // B*T
#define K_DIM 8192
#define N_DIM 8192
#define NGRP  64      // N/128 groups

// Tile config
#define BN 128        // W rows per block
#define BK 32         // n per step
#define THREADS 512   // 8 waves
#define SPLITN 8
#define CHUNK  (N_DIM / SPLITN)   // 1024
#define NSTEPS (CHUNK / BK)       // 32
#define NG     (CHUNK >> 7)       // 8 groups per chunk

// LDS layout: A triple-buffered (glds), B single (reg-staged bf16), SL scales
#define ASIZE 16384               // bf16 [256][32]
#define BSIZE 8192                // bf16 [128][32]
#define B_OFF  (3 * ASIZE)
#define SL_OFF (3 * ASIZE + BSIZE)
#define LDS_TOTAL (SL_OFF + NG * 128 * 8)   // 48K + 8K + 8K = 64KB

typedef __bf16 bf16x8 __attribute__((ext_vector_type(8)));
typedef __bf16 bf16x4 __attribute__((ext_vector_type(4)));
typedef float  f32x4  __attribute__((ext_vector_type(4)));

// XOR swizzle for the A region (involution within 1KB)
#define SW(a) ((a) ^ ((((a) >> 7) & 7) << 4))

#define GLOAD_LDS16(g, l) __builtin_amdgcn_global_load_lds( \
    (const __attribute__((address_space(1))) void*)(g),     \
    (__attribute__((address_space(3))) void*)(l), 16, 0, 0)

// ---------------- Kernel 0: xs[m,n] = bf16(x[m,n] * mu1[n]) ----------------
__global__ __launch_bounds__(256) void prep_xs(const float* __restrict__ x,
                                               const float* __restrict__ mu1,
                                               __bf16* __restrict__ xs) {
    int t  = blockIdx.x * 256 + threadIdx.x;
    int n4 = t & 2047;
    int m  = t >> 11;
    int n  = n4 << 2;
    float4 xv = *(const float4*)(x + (size_t)m * N_DIM + n);
    float4 mv = *(const float4*)(mu1 + n);
    bf16x4 o;
    o[0] = (__bf16)(xv.x * mv.x);
    o[1] = (__bf16)(xv.y * mv.y);
    o[2] = (__bf16)(xv.z * mv.z);
    o[3] = (__bf16)(xv.w * mv.w);
    *(bf16x4*)(xs + (size_t)m * N_DIM + n) = o;
}

// ---------------- Kernel 1: 2-block/CU pipelined split-K GEMM ----------------
__global__ __launch_bounds__(THREADS, 4)
void gemm_q(const __bf16* __restrict__ xs, const int* __restrict__ Wq,
            const float* __restrict__ scales, const float* __restrict__ zeros,
            float* __restrict__ partial) {
    extern __shared__ __align__(1024) char lds[];

    const int b     = blockIdx.x;      // 512 blocks
    const int split = b & 7;           // XCD-affine: one split per XCD
    const int kidx  = b >> 3;          // 0..63
    const int k0    = kidx * BN;
    const int nbase = split * CHUNK;
    const int gbase = split * NG;

    const int tid  = threadIdx.x;
    const int lane = tid & 63;
    const int w    = tid >> 6;   // 0..7
    const int wm   = w >> 2;     // m half
    const int wn   = w & 3;      // k quarter
    const int start = kidx & (NSTEPS - 1);   // n-rotation

    float* SL = (float*)(lds + SL_OFF);      // [NG][128] x {s, -z*s}

    // ---- stage scales/zeros (once) ----
    {
        int r = tid >> 2, gq = tid & 3;
#pragma unroll
        for (int gg = 0; gg < (NG >> 2); ++gg) {
            int g = (gg << 2) | gq;
            size_t si = (size_t)(k0 + r) * NGRP + gbase + g;
            float s = scales[si];
            float z = zeros[si];
            float2 v; v.x = s; v.y = -z * s;
            *(float2*)&SL[(size_t)((g << 7) + r) * 2] = v;
        }
    }

    // ---- A staging via global_load_lds: 2x 1KB chunks per wave ----
    const char* asrc[2];
    int aoff[2];
#pragma unroll
    for (int cc = 0; cc < 2; ++cc) {
        int c   = w * 2 + cc;            // 0..15
        int off = c * 1024 + lane * 16;  // linear LDS dest
        int L   = SW(off);               // logical element (inverse-swizzled src)
        aoff[cc] = off;
        asrc[cc] = (const char*)xs + ((size_t)(L >> 6) * N_DIM) * 2 + (L & 63);
    }

    // ---- B reg-staging: each lane owns row 16w+(l>>2), 8 codes at col (l&3)*8 ----
    const int brow = w * 16 + (lane >> 2);        // 0..127
    const int bq   = lane & 3;
    const int* bptr0 = Wq + (size_t)(k0 + brow) * N_DIM + bq * 8;
    char* bdst = lds + B_OFF + brow * 64 + bq * 16;   // bf16 dest, 16B/lane

#define ISSUE_A(t)                                                        \
    {                                                                     \
        int s_ = ((t) + start) & (NSTEPS - 1);                            \
        char* bs_ = lds + ((t) % 3) * ASIZE;                              \
        size_t so_ = (size_t)(nbase + s_ * BK) * 2;                       \
        GLOAD_LDS16(asrc[0] + so_, bs_ + aoff[0]);                        \
        GLOAD_LDS16(asrc[1] + so_, bs_ + aoff[1]);                        \
    }
#define LOAD_B(t, q0, q1)                                                 \
    {                                                                     \
        int s_ = ((t) + start) & (NSTEPS - 1);                            \
        const int* p_ = bptr0 + (nbase + s_ * BK);                        \
        q0 = *(const int4*)p_;                                            \
        q1 = *(const int4*)(p_ + 4);                                      \
    }

    f32x4 acc[8][2];
#pragma unroll
    for (int i = 0; i < 8; ++i) {
        acc[i][0] = (f32x4){0.f, 0.f, 0.f, 0.f};
        acc[i][1] = (f32x4){0.f, 0.f, 0.f, 0.f};
    }

    int4 qa0, qa1, qb0, qb1;

    // prologue: B(0) to regs, A(0), A(1) to LDS  (outstanding: B0,A0,A1)
    LOAD_B(0, qa0, qa1);
    ISSUE_A(0);
    ISSUE_A(1);

#define STEP(it, q0c, q1c, q0n, q1n)                                      \
    {                                                                     \
        /* phase1: A(it) landed + B(it) regs ready; A(it+1) stays out */  \
        if ((it) < NSTEPS - 1) asm volatile("s_waitcnt vmcnt(2)" ::: "memory"); \
        else                   asm volatile("s_waitcnt vmcnt(0)" ::: "memory"); \
        __builtin_amdgcn_s_barrier();  /* everyone done reading B/prev A */ \
        /* phase2: dequant B(it) -> LDS (bf16) */                         \
        int scur_ = ((it) + start) & (NSTEPS - 1);                        \
        float2 sz_ = *(float2*)&SL[(size_t)(((scur_ >> 2) << 7) + brow) * 2]; \
        bf16x8 wv_;                                                       \
        wv_[0] = (__bf16)((float)q0c.x * sz_.x + sz_.y);                  \
        wv_[1] = (__bf16)((float)q0c.y * sz_.x + sz_.y);                  \
        wv_[2] = (__bf16)((float)q0c.z * sz_.x + sz_.y);                  \
        wv_[3] = (__bf16)((float)q0c.w * sz_.x + sz_.y);                  \
        wv_[4] = (__bf16)((float)q1c.x * sz_.x + sz_.y);                  \
        wv_[5] = (__bf16)((float)q1c.y * sz_.x + sz_.y);                  \
        wv_[6] = (__bf16)((float)q1c.z * sz_.x + sz_.y);                  \
        wv_[7] = (__bf16)((float)q1c.w * sz_.x + sz_.y);                  \
        *(bf16x8*)bdst = wv_;                                             \
        asm volatile("s_waitcnt lgkmcnt(0)" ::: "memory");                \
        __builtin_amdgcn_s_barrier();  /* B tile visible to all */        \
        /* phase3: issue next loads */                                    \
        if ((it) + 1 < NSTEPS) LOAD_B((it) + 1, q0n, q1n);                \
        if ((it) + 2 < NSTEPS) ISSUE_A((it) + 2);                         \
        /* phase4: fragments + MFMA */                                    \
        const char* bufA_ = lds + ((it) % 3) * ASIZE;                     \
        const char* bufB_ = lds + B_OFF;                                  \
        bf16x8 bv_[2];                                                    \
        _Pragma("unroll")                                                 \
        for (int ci = 0; ci < 2; ++ci) {                                  \
            int r_ = wn * 32 + ci * 16 + (lane & 15);                     \
            bv_[ci] = *(const bf16x8*)(bufB_ + r_ * 64 + (lane >> 4) * 16); \
        }                                                                 \
        _Pragma("unroll")                                                 \
        for (int mi = 0; mi < 8; ++mi) {                                  \
            int la_ = (wm * 128 + mi * 16 + (lane & 15)) * 64 + (lane >> 4) * 16; \
            bf16x8 av_ = *(const bf16x8*)(bufA_ + SW(la_));               \
            acc[mi][0] = __builtin_amdgcn_mfma_f32_16x16x32_bf16(av_, bv_[0], acc[mi][0], 0, 0, 0); \
            acc[mi][1] = __builtin_amdgcn_mfma_f32_16x16x32_bf16(av_, bv_[1], acc[mi][1], 0, 0, 0); \
        }                                                                 \
    }

    for (int it = 0; it < NSTEPS; it += 2) {
        STEP(it,     qa0, qa1, qb0, qb1);
        STEP(it + 1, qb0, qb1, qa0, qa1);
    }
#undef STEP
#undef ISSUE_A
#undef LOAD_B

    // ---- epilogue: fp32 partials (C/D: col=lane&15, row=(lane>>4)*4+reg) ----
    float* outp = partial + (size_t)split * ((size_t)M_DIM * K_DIM);
#pragma unroll
    for (int mi = 0; mi < 8; ++mi) {
#pragma unroll
        for (int ci = 0; ci < 2; ++ci) {
            int gk = k0 + wn * 32 + ci * 16 + (lane & 15);
            int gm = wm * 128 + mi * 16 + (lane >> 4) * 4;
#pragma unroll
            for (int rix = 0; rix < 4; ++rix)
                outp[(size_t)(gm + rix) * K_DIM + gk] = acc[mi][ci][rix];
        }
    }
}

// ---------------- Kernel 2: out = mu2[k] * sum_splits + bias[k] ----------------
__global__ __launch_bounds__(256) void reduce_out(const float* __restrict__ partial,
                                                  const float* __restrict__ mu2,
                                                  const float* __restrict__ bias,
                                                  float* __restrict__ out) {
    int t  = blockIdx.x * 256 + threadIdx.x;
    int k4 = t & 2047;
    int m  = t >> 11;
    size_t base = (size_t)m * K_DIM + (size_t)k4 * 4;
    float4 s = *(const float4*)(partial + base);
    for (int sp = 1; sp < SPLITN; ++sp) {
        float4 p = *(const float4*)(partial + (size_t)sp * ((size_t)M_DIM * K_DIM) + base);
        s.x += p.x; s.y += p.y; s.z += p.z; s.w += p.w;
    }
    float4 m2 = *(const float4*)(mu2 + (size_t)k4 * 4);
    float4 bi = *(const float4*)(bias + (size_t)k4 * 4);
    float4 o;
    o.x = s.x * m2.x + bi.x;
    o.y = s.y * m2.y + bi.y;
    o.z = s.z * m2.z + bi.z;
    o.w = s.w * m2.w + bi.w;
    *(float4*)(out + base) = o;
}

extern "C" void kernel_launch(void* const* d_in, const int* in_sizes, int n_in,
                              void* d_out, int out_size, void* d_ws, size_t ws_size,
                              hipStream_t stream) {
    const float* x      = (const float*)d_in[0];
    const int*   Wq     = (const int*)d_in[1];
    const float* scales = (const float*)d_in[2];
    const float* zeros  = (const float*)d_in[3];
    const float* mu1    = (const float*)d_in[4];
    const float* mu2    = (const float*)d_in[5];
    const float* bias   = (const float*)d_in[6];
    float* out = (float*)d_out;

    __bf16* xs = (__bf16*)d_ws;
    const size_t xs_bytes = (size_t)M_DIM * N_DIM * sizeof(__bf16);   // 4 MB
    float* partial = (float*)((char*)d_ws + xs_bytes);                 // 8 x 8 MB

    (void)hipFuncSetAttribute((const void*)gemm_q,
                              hipFuncAttributeMaxDynamicSharedMemorySize,
                              LDS_TOTAL);

    prep_xs<<<2048, 256, 0, stream>>>(x, mu1, xs);
    gemm_q<<<64 * SPLITN, THREADS, LDS_TOTAL, stream>>>(xs, Wq, scales, zeros, partial);
    reduce_out<<<2048, 256, 0, stream>>>(partial, mu2, bias, out);
}

// Round 6
// 89.774 us; speedup vs baseline: 1.8083x; 1.0882x over previous
//
#include <hip/hip_runtime.h>
#include <hip/hip_bf16.h>

// Problem constants
#define M_DIM 256     // B*T
#define K_DIM 8192
#define N_DIM 8192
#define NGRP  64      // N/128 groups

// Tile config
#define BN 128        // W rows per block
#define BK 32         // n per step
#define THREADS 512   // 8 waves
#define SPLITN 8
#define CHUNK  (N_DIM / SPLITN)   // 1024
#define NSTEPS (CHUNK / BK)       // 32
#define NG     (CHUNK >> 7)       // 8 groups per chunk

// LDS layout: A triple-buffered (glds), B single (reg-staged bf16), SL scales
#define ASIZE 16384               // bf16 [256][32]
#define BSIZE 8192                // bf16 [128][32]
#define B_OFF  (3 * ASIZE)
#define SL_OFF (3 * ASIZE + BSIZE)
#define LDS_TOTAL (SL_OFF + NG * 128 * 8)   // 48K + 8K + 8K = 64KB

typedef __bf16 bf16x8 __attribute__((ext_vector_type(8)));
typedef __bf16 bf16x4 __attribute__((ext_vector_type(4)));
typedef float  f32x4  __attribute__((ext_vector_type(4)));

// XOR swizzle for the A region (involution within 1KB)
#define SW(a) ((a) ^ ((((a) >> 7) & 7) << 4))

#define GLOAD_LDS16(g, l) __builtin_amdgcn_global_load_lds( \
    (const __attribute__((address_space(1))) void*)(g),     \
    (__attribute__((address_space(3))) void*)(l), 16, 0, 0)

// ---------------- Kernel 0: xs[m,n] = bf16(x[m,n] * mu1[n]) ----------------
__global__ __launch_bounds__(256) void prep_xs(const float* __restrict__ x,
                                               const float* __restrict__ mu1,
                                               __bf16* __restrict__ xs) {
    int t  = blockIdx.x * 256 + threadIdx.x;
    int n4 = t & 2047;
    int m  = t >> 11;
    int n  = n4 << 2;
    float4 xv = *(const float4*)(x + (size_t)m * N_DIM + n);
    float4 mv = *(const float4*)(mu1 + n);
    bf16x4 o;
    o[0] = (__bf16)(xv.x * mv.x);
    o[1] = (__bf16)(xv.y * mv.y);
    o[2] = (__bf16)(xv.z * mv.z);
    o[3] = (__bf16)(xv.w * mv.w);
    *(bf16x4*)(xs + (size_t)m * N_DIM + n) = o;
}

// ---------------- Kernel 1: 2-block/CU, depth-2 symmetric pipeline ----------------
__global__ __launch_bounds__(THREADS, 4)
void gemm_q(const __bf16* __restrict__ xs, const int* __restrict__ Wq,
            const float* __restrict__ scales, const float* __restrict__ zeros,
            __bf16* __restrict__ partial) {
    extern __shared__ __align__(1024) char lds[];

    const int b     = blockIdx.x;      // 512 blocks
    const int split = b & 7;           // XCD-affine: one split per XCD
    const int kidx  = b >> 3;          // 0..63
    const int k0    = kidx * BN;
    const int nbase = split * CHUNK;
    const int gbase = split * NG;

    const int tid  = threadIdx.x;
    const int lane = tid & 63;
    const int w    = tid >> 6;   // 0..7
    const int wm   = w >> 2;     // m half
    const int wn   = w & 3;      // k quarter
    const int start = kidx & (NSTEPS - 1);   // n-rotation

    float* SL = (float*)(lds + SL_OFF);      // [NG][128] x {s, -z*s}

    // ---- stage scales/zeros (once) ----
    {
        int r = tid >> 2, gq = tid & 3;
#pragma unroll
        for (int gg = 0; gg < (NG >> 2); ++gg) {
            int g = (gg << 2) | gq;
            size_t si = (size_t)(k0 + r) * NGRP + gbase + g;
            float s = scales[si];
            float z = zeros[si];
            float2 v; v.x = s; v.y = -z * s;
            *(float2*)&SL[(size_t)((g << 7) + r) * 2] = v;
        }
    }

    // ---- A staging via global_load_lds: 2x 1KB chunks per wave ----
    const char* asrc[2];
    int aoff[2];
#pragma unroll
    for (int cc = 0; cc < 2; ++cc) {
        int c   = w * 2 + cc;            // 0..15
        int off = c * 1024 + lane * 16;  // linear LDS dest
        int L   = SW(off);               // logical element (inverse-swizzled src)
        aoff[cc] = off;
        asrc[cc] = (const char*)xs + ((size_t)(L >> 6) * N_DIM) * 2 + (L & 63);
    }

    // ---- B reg-staging: each lane owns row 16w+(l>>2), 8 codes at col (l&3)*8 ----
    const int brow = w * 16 + (lane >> 2);        // 0..127
    const int bq   = lane & 3;
    const int* bptr0 = Wq + (size_t)(k0 + brow) * N_DIM + bq * 8;
    char* bdst = lds + B_OFF + brow * 64 + bq * 16;   // bf16 dest, 16B/lane

#define ISSUE_A(t)                                                        \
    {                                                                     \
        int s_ = ((t) + start) & (NSTEPS - 1);                            \
        char* bs_ = lds + ((t) % 3) * ASIZE;                              \
        size_t so_ = (size_t)(nbase + s_ * BK) * 2;                       \
        GLOAD_LDS16(asrc[0] + so_, bs_ + aoff[0]);                        \
        GLOAD_LDS16(asrc[1] + so_, bs_ + aoff[1]);                        \
    }
#define LOAD_B(t, q0, q1)                                                 \
    {                                                                     \
        int s_ = ((t) + start) & (NSTEPS - 1);                            \
        const int* p_ = bptr0 + (nbase + s_ * BK);                        \
        q0 = *(const int4*)p_;                                            \
        q1 = *(const int4*)(p_ + 4);                                      \
    }

    f32x4 acc[8][2];
#pragma unroll
    for (int i = 0; i < 8; ++i) {
        acc[i][0] = (f32x4){0.f, 0.f, 0.f, 0.f};
        acc[i][1] = (f32x4){0.f, 0.f, 0.f, 0.f};
    }

    int4 qa0, qa1, qb0, qb1;

    // prologue: step-0 loads (B0 regs + A0 lds), fence, step-1 loads.
    // FIFO: [B0,A0 | B1,A1] -> vmcnt(4) at step0 drains exactly step-0's 4.
    LOAD_B(0, qa0, qa1);
    ISSUE_A(0);
    asm volatile("" ::: "memory");
    LOAD_B(1, qb0, qb1);
    ISSUE_A(1);

    // STEP: phase1 wait+barrier | phase2 dequant B(it)->LDS | phase3 issue
    // B(it+2) into just-consumed regs + A(it+2) | phase4 frags+MFMA.
#define STEP(it, q0c, q1c)                                                \
    {                                                                     \
        if ((it) < NSTEPS - 1) asm volatile("s_waitcnt vmcnt(4)" ::: "memory"); \
        else                   asm volatile("s_waitcnt vmcnt(0)" ::: "memory"); \
        __builtin_amdgcn_s_barrier();  /* everyone done reading B/prev A */ \
        int scur_ = ((it) + start) & (NSTEPS - 1);                        \
        float2 sz_ = *(float2*)&SL[(size_t)(((scur_ >> 2) << 7) + brow) * 2]; \
        bf16x8 wv_;                                                       \
        wv_[0] = (__bf16)((float)q0c.x * sz_.x + sz_.y);                  \
        wv_[1] = (__bf16)((float)q0c.y * sz_.x + sz_.y);                  \
        wv_[2] = (__bf16)((float)q0c.z * sz_.x + sz_.y);                  \
        wv_[3] = (__bf16)((float)q0c.w * sz_.x + sz_.y);                  \
        wv_[4] = (__bf16)((float)q1c.x * sz_.x + sz_.y);                  \
        wv_[5] = (__bf16)((float)q1c.y * sz_.x + sz_.y);                  \
        wv_[6] = (__bf16)((float)q1c.z * sz_.x + sz_.y);                  \
        wv_[7] = (__bf16)((float)q1c.w * sz_.x + sz_.y);                  \
        *(bf16x8*)bdst = wv_;                                             \
        asm volatile("s_waitcnt lgkmcnt(0)" ::: "memory");                \
        __builtin_amdgcn_s_barrier();  /* B tile visible to all */        \
        if ((it) + 2 < NSTEPS) {                                          \
            LOAD_B((it) + 2, q0c, q1c);                                   \
            ISSUE_A((it) + 2);                                            \
        }                                                                 \
        const char* bufA_ = lds + ((it) % 3) * ASIZE;                     \
        const char* bufB_ = lds + B_OFF;                                  \
        bf16x8 bv_[2];                                                    \
        _Pragma("unroll")                                                 \
        for (int ci = 0; ci < 2; ++ci) {                                  \
            int r_ = wn * 32 + ci * 16 + (lane & 15);                     \
            bv_[ci] = *(const bf16x8*)(bufB_ + r_ * 64 + (lane >> 4) * 16); \
        }                                                                 \
        _Pragma("unroll")                                                 \
        for (int mi = 0; mi < 8; ++mi) {                                  \
            int la_ = (wm * 128 + mi * 16 + (lane & 15)) * 64 + (lane >> 4) * 16; \
            bf16x8 av_ = *(const bf16x8*)(bufA_ + SW(la_));               \
            acc[mi][0] = __builtin_amdgcn_mfma_f32_16x16x32_bf16(av_, bv_[0], acc[mi][0], 0, 0, 0); \
            acc[mi][1] = __builtin_amdgcn_mfma_f32_16x16x32_bf16(av_, bv_[1], acc[mi][1], 0, 0, 0); \
        }                                                                 \
    }

    for (int it = 0; it < NSTEPS; it += 2) {
        STEP(it,     qa0, qa1);
        STEP(it + 1, qb0, qb1);
    }
#undef STEP
#undef ISSUE_A
#undef LOAD_B

    // ---- epilogue: bf16 partials (C/D: col=lane&15, row=(lane>>4)*4+reg) ----
    __bf16* outp = partial + (size_t)split * ((size_t)M_DIM * K_DIM);
#pragma unroll
    for (int mi = 0; mi < 8; ++mi) {
#pragma unroll
        for (int ci = 0; ci < 2; ++ci) {
            int gk = k0 + wn * 32 + ci * 16 + (lane & 15);
            int gm = wm * 128 + mi * 16 + (lane >> 4) * 4;
#pragma unroll
            for (int rix = 0; rix < 4; ++rix)
                outp[(size_t)(gm + rix) * K_DIM + gk] = (__bf16)acc[mi][ci][rix];
        }
    }
}

// ---------------- Kernel 2: out = mu2[k] * sum_splits + bias[k] ----------------
__global__ __launch_bounds__(256) void reduce_out(const __bf16* __restrict__ partial,
                                                  const float* __restrict__ mu2,
                                                  const float* __restrict__ bias,
                                                  float* __restrict__ out) {
    int t  = blockIdx.x * 256 + threadIdx.x;
    int k4 = t & 2047;
    int m  = t >> 11;
    size_t base = (size_t)m * K_DIM + (size_t)k4 * 4;
    float4 s; s.x = 0.f; s.y = 0.f; s.z = 0.f; s.w = 0.f;
#pragma unroll
    for (int sp = 0; sp < SPLITN; ++sp) {
        bf16x4 p = *(const bf16x4*)(partial + (size_t)sp * ((size_t)M_DIM * K_DIM) + base);
        s.x += (float)p[0]; s.y += (float)p[1]; s.z += (float)p[2]; s.w += (float)p[3];
    }
    float4 m2 = *(const float4*)(mu2 + (size_t)k4 * 4);
    float4 bi = *(const float4*)(bias + (size_t)k4 * 4);
    float4 o;
    o.x = s.x * m2.x + bi.x;
    o.y = s.y * m2.y + bi.y;
    o.z = s.z * m2.z + bi.z;
    o.w = s.w * m2.w + bi.w;
    *(float4*)(out + base) = o;
}

extern "C" void kernel_launch(void* const* d_in, const int* in_sizes, int n_in,
                              void* d_out, int out_size, void* d_ws, size_t ws_size,
                              hipStream_t stream) {
    const float* x      = (const float*)d_in[0];
    const int*   Wq     = (const int*)d_in[1];
    const float* scales = (const float*)d_in[2];
    const float* zeros  = (const float*)d_in[3];
    const float* mu1    = (const float*)d_in[4];
    const float* mu2    = (const float*)d_in[5];
    const float* bias   = (const float*)d_in[6];
    float* out = (float*)d_out;

    __bf16* xs = (__bf16*)d_ws;
    const size_t xs_bytes = (size_t)M_DIM * N_DIM * sizeof(__bf16);   // 4 MB
    __bf16* partial = (__bf16*)((char*)d_ws + xs_bytes);              // 8 x 4 MB

    (void)hipFuncSetAttribute((const void*)gemm_q,
                              hipFuncAttributeMaxDynamicSharedMemorySize,
                              LDS_TOTAL);

    prep_xs<<<2048, 256, 0, stream>>>(x, mu1, xs);
    gemm_q<<<64 * SPLITN, THREADS, LDS_TOTAL, stream>>>(xs, Wq, scales, zeros, partial);
    reduce_out<<<2048, 256, 0, stream>>>(partial, mu2, bias, out);
}